// Round 4
// baseline (1095.136 us; speedup 1.0000x reference)
//
#include <hip/hip_runtime.h>
#include <math.h>

#define D1 128
#define NEG 0.2f

__device__ __forceinline__ float lrelu(float v){ return v > 0.f ? v : NEG * v; }
__device__ __forceinline__ float elu_f(float v){ return v > 0.f ? v : __expf(v) - 1.f; }

__device__ __forceinline__ unsigned bf16rne(float f){
    unsigned u = __float_as_uint(f);
    return (u + 0x7fffu + ((u >> 16) & 1u)) >> 16;     // upper 16 bits, RNE
}

// ---------------- CSR build ----------------

__global__ void k_hist(const int* __restrict__ ei, int* __restrict__ deg,
                       int n_edges, int etot){
    int e = blockIdx.x * 256 + threadIdx.x;
    if (e >= etot) return;
    int dst = (e < n_edges) ? ei[n_edges + e] : (e - n_edges);
    atomicAdd(&deg[dst], 1);
}

__global__ __launch_bounds__(1024) void k_scan1(const int* __restrict__ deg,
                                                int* __restrict__ rowptr,
                                                int* __restrict__ bsum, int n){
    __shared__ int sd[1024];
    int i = blockIdx.x * 1024 + threadIdx.x;
    int v = (i < n) ? deg[i] : 0;
    sd[threadIdx.x] = v;
    __syncthreads();
    for (int off = 1; off < 1024; off <<= 1){
        int t = (threadIdx.x >= off) ? sd[threadIdx.x - off] : 0;
        __syncthreads();
        sd[threadIdx.x] += t;
        __syncthreads();
    }
    if (i < n) rowptr[i] = sd[threadIdx.x] - v;      // exclusive scan
    if (threadIdx.x == 1023) bsum[blockIdx.x] = sd[1023];
}

__global__ void k_scan2(int* bsum, int nb){
    if (threadIdx.x == 0){
        int run = 0;
        for (int b = 0; b < nb; b++){ int t = bsum[b]; bsum[b] = run; run += t; }
    }
}

__global__ __launch_bounds__(1024) void k_scan3(int* __restrict__ rowptr,
                                                int* __restrict__ cursor,
                                                const int* __restrict__ bsum,
                                                int n, int etot){
    int i = blockIdx.x * 1024 + threadIdx.x;
    if (i < n){
        int v = rowptr[i] + bsum[blockIdx.x];
        rowptr[i] = v;
        cursor[i] = v;
    }
    if (i == 0) rowptr[n] = etot;
}

__global__ void k_scatter(const int* __restrict__ ei, int* __restrict__ cursor,
                          int* __restrict__ eidx, int n_edges, int etot){
    int e = blockIdx.x * 256 + threadIdx.x;
    if (e >= etot) return;
    int src, dst;
    if (e < n_edges){ src = ei[e]; dst = ei[n_edges + e]; }
    else            { src = dst = e - n_edges; }
    int pos = atomicAdd(&cursor[dst], 1);
    eidx[pos] = src;
}

// ---------------- weight transpose: WT[k*128+j] = W[j*128+k] ----------------

__global__ void k_transw(const float* __restrict__ W1, const float* __restrict__ W2,
                         const float* __restrict__ W3, float* __restrict__ WT){
    int t = blockIdx.x * 256 + threadIdx.x;          // 0..49151
    int w = t >> 14;
    int r = t & 16383;
    int k = r >> 7, j = r & 127;
    const float* W = (w == 0) ? W1 : (w == 1) ? W2 : W3;
    WT[t] = W[j * 128 + k];
}

// ---------------- fp32 GEMM: H[n][j] = sum_k X[n][k] * WT[k][j] ----------------
// Optionally also writes a bf16 (RNE) mirror Hb[n][128] for the gather kernel.

__global__ __launch_bounds__(256) void k_gemm(const float* __restrict__ X,
                                              const float* __restrict__ WT,
                                              float* __restrict__ H,
                                              unsigned* __restrict__ Hb, int n_rows){
    __shared__ float xs[64 * 128];     // 32 KB
    __shared__ float wsm[32 * 128];    // 16 KB
    int tx = threadIdx.x & 31;         // col group: j0 = 4*tx
    int ty = threadIdx.x >> 5;         // row group: r0 = 8*ty
    int row0 = blockIdx.x * 64;

    #pragma unroll
    for (int i = 0; i < 8; i++){
        int idx = threadIdx.x + i * 256;
        int r = idx >> 5, c = idx & 31;
        float4 v = make_float4(0.f, 0.f, 0.f, 0.f);
        if (row0 + r < n_rows) v = ((const float4*)X)[(size_t)(row0 + r) * 32 + c];
        ((float4*)xs)[idx] = v;
    }

    float4 acc[8];
    #pragma unroll
    for (int i = 0; i < 8; i++) acc[i] = make_float4(0.f, 0.f, 0.f, 0.f);

    for (int k0 = 0; k0 < 128; k0 += 32){
        __syncthreads();
        #pragma unroll
        for (int i = 0; i < 4; i++){
            int idx = threadIdx.x + i * 256;
            ((float4*)wsm)[idx] = ((const float4*)(WT + k0 * 128))[idx];
        }
        __syncthreads();
        #pragma unroll
        for (int kk4 = 0; kk4 < 8; kk4++){
            float4 wv0 = ((float4*)wsm)[(kk4 * 4 + 0) * 32 + tx];
            float4 wv1 = ((float4*)wsm)[(kk4 * 4 + 1) * 32 + tx];
            float4 wv2 = ((float4*)wsm)[(kk4 * 4 + 2) * 32 + tx];
            float4 wv3 = ((float4*)wsm)[(kk4 * 4 + 3) * 32 + tx];
            #pragma unroll
            for (int i = 0; i < 8; i++){
                float4 xv = ((float4*)xs)[(ty * 8 + i) * 32 + (k0 >> 2) + kk4];
                acc[i].x += xv.x * wv0.x + xv.y * wv1.x + xv.z * wv2.x + xv.w * wv3.x;
                acc[i].y += xv.x * wv0.y + xv.y * wv1.y + xv.z * wv2.y + xv.w * wv3.y;
                acc[i].z += xv.x * wv0.z + xv.y * wv1.z + xv.z * wv2.z + xv.w * wv3.z;
                acc[i].w += xv.x * wv0.w + xv.y * wv1.w + xv.z * wv2.w + xv.w * wv3.w;
            }
        }
    }
    #pragma unroll
    for (int i = 0; i < 8; i++){
        int r = row0 + ty * 8 + i;
        if (r < n_rows){
            ((float4*)H)[(size_t)r * 32 + tx] = acc[i];
            if (Hb){
                unsigned w0 = bf16rne(acc[i].x) | (bf16rne(acc[i].y) << 16);
                unsigned w1 = bf16rne(acc[i].z) | (bf16rne(acc[i].w) << 16);
                ((uint2*)(Hb + (size_t)r * 64))[tx] = make_uint2(w0, w1);
            }
        }
    }
}

// ---------------- attention coefficients ----------------

__global__ void k_att(const float* __restrict__ H, const float* __restrict__ aw_s,
                      const float* __restrict__ aw_d, float* __restrict__ asrc,
                      float* __restrict__ adst, int n_nodes){
    int t = blockIdx.x * 256 + threadIdx.x;
    if (t >= n_nodes * 4) return;
    int n = t >> 2, hd = t & 3;
    const float4* hp = (const float4*)(H + (size_t)n * 128 + hd * 32);
    const float4* sp = (const float4*)(aw_s + hd * 32);
    const float4* dp = (const float4*)(aw_d + hd * 32);
    float s = 0.f, d = 0.f;
    #pragma unroll
    for (int i = 0; i < 8; i++){
        float4 h4 = hp[i], s4 = sp[i], d4 = dp[i];
        s += h4.x * s4.x + h4.y * s4.y + h4.z * s4.z + h4.w * s4.w;
        d += h4.x * d4.x + h4.y * d4.y + h4.z * d4.z + h4.w * d4.w;
    }
    asrc[t] = s;
    adst[t] = d;
}

// ---------------- softmax + aggregation, one wave per node ----------------
// BF16=1: gather from bf16 mirror (half the bytes). 8-edge ILP batching.

#define AGGR_CAP 96

template<int MEAN, int BF16>
__global__ __launch_bounds__(256) void k_aggr(const float* __restrict__ H,
        const unsigned* __restrict__ Hb,
        const float* __restrict__ asrc, const float* __restrict__ adst,
        const int* __restrict__ rowptr, const int* __restrict__ eidx,
        const float* __restrict__ bias, float* __restrict__ Out, int n_nodes){
    __shared__ float wls[4][AGGR_CAP * 4];     // 6 KB
    int lane = threadIdx.x & 63;
    int wid  = threadIdx.x >> 6;
    int n = blockIdx.x * 4 + wid;
    if (n >= n_nodes) return;
    int row0 = rowptr[n];
    int deg  = rowptr[n + 1] - row0;
    float4 ad = ((const float4*)adst)[n];
    float* wl = wls[wid];
    const int* ep = eidx + row0;

    // Phase A: edge scores (first strided round cached in regs) + max
    float e0 = -1e30f, e1 = -1e30f, e2 = -1e30f, e3 = -1e30f;
    if (lane < deg){
        int s = ep[lane];
        float4 av = ((const float4*)asrc)[s];
        e0 = lrelu(av.x + ad.x); e1 = lrelu(av.y + ad.y);
        e2 = lrelu(av.z + ad.z); e3 = lrelu(av.w + ad.w);
    }
    float m0 = e0, m1 = e1, m2 = e2, m3 = e3;
    for (int i = lane + 64; i < deg; i += 64){   // rare (deg > 64)
        int s = ep[i];
        float4 av = ((const float4*)asrc)[s];
        m0 = fmaxf(m0, lrelu(av.x + ad.x));
        m1 = fmaxf(m1, lrelu(av.y + ad.y));
        m2 = fmaxf(m2, lrelu(av.z + ad.z));
        m3 = fmaxf(m3, lrelu(av.w + ad.w));
    }
    #pragma unroll
    for (int off = 32; off; off >>= 1){
        m0 = fmaxf(m0, __shfl_xor(m0, off));
        m1 = fmaxf(m1, __shfl_xor(m1, off));
        m2 = fmaxf(m2, __shfl_xor(m2, off));
        m3 = fmaxf(m3, __shfl_xor(m3, off));
    }

    // Phase B: unnormalized exp -> LDS, accumulate denom
    float d0 = 0.f, d1 = 0.f, d2 = 0.f, d3 = 0.f;
    if (lane < deg){
        float x0 = __expf(e0 - m0), x1 = __expf(e1 - m1);
        float x2 = __expf(e2 - m2), x3 = __expf(e3 - m3);
        d0 = x0; d1 = x1; d2 = x2; d3 = x3;
        ((float4*)wl)[lane] = make_float4(x0, x1, x2, x3);
    }
    for (int i = lane + 64; i < deg; i += 64){   // rare
        int s = ep[i];
        float4 av = ((const float4*)asrc)[s];
        float x0 = __expf(lrelu(av.x + ad.x) - m0);
        float x1 = __expf(lrelu(av.y + ad.y) - m1);
        float x2 = __expf(lrelu(av.z + ad.z) - m2);
        float x3 = __expf(lrelu(av.w + ad.w) - m3);
        d0 += x0; d1 += x1; d2 += x2; d3 += x3;
        if (i < AGGR_CAP) ((float4*)wl)[i] = make_float4(x0, x1, x2, x3);
    }
    #pragma unroll
    for (int off = 32; off; off >>= 1){
        d0 += __shfl_xor(d0, off);
        d1 += __shfl_xor(d1, off);
        d2 += __shfl_xor(d2, off);
        d3 += __shfl_xor(d3, off);
    }
    int hd = lane >> 4;
    float mh  = hd == 0 ? m0 : hd == 1 ? m1 : hd == 2 ? m2 : m3;
    float rdh = 1.f / (hd == 0 ? d0 : hd == 1 ? d1 : hd == 2 ? d2 : d3);
    float adh = hd == 0 ? ad.x : hd == 1 ? ad.y : hd == 2 ? ad.z : ad.w;

    // Phase C: acc = sum_e w_e * h_e ; normalize once at the end
    float accx = 0.f, accy = 0.f;
    int c = lane * 2;
    const float* wlh = wl + hd;
    int cap = deg < AGGR_CAP ? deg : AGGR_CAP;
    int i = 0;
    for (; i + 8 <= cap; i += 8){
        int s[8];
        #pragma unroll
        for (int j = 0; j < 8; j++) s[j] = ep[i + j];
        if (BF16){
            unsigned hw[8];
            #pragma unroll
            for (int j = 0; j < 8; j++) hw[j] = Hb[(size_t)s[j] * 64 + lane];
            #pragma unroll
            for (int j = 0; j < 8; j++){
                float w = wlh[(i + j) * 4];
                accx += w * __uint_as_float(hw[j] << 16);
                accy += w * __uint_as_float(hw[j] & 0xffff0000u);
            }
        } else {
            float2 hv[8];
            #pragma unroll
            for (int j = 0; j < 8; j++) hv[j] = *(const float2*)(H + (size_t)s[j] * 128 + c);
            #pragma unroll
            for (int j = 0; j < 8; j++){
                float w = wlh[(i + j) * 4];
                accx += w * hv[j].x;
                accy += w * hv[j].y;
            }
        }
    }
    for (; i < cap; i++){
        int s = ep[i];
        float w = wlh[i * 4];
        if (BF16){
            unsigned hw = Hb[(size_t)s * 64 + lane];
            accx += w * __uint_as_float(hw << 16);
            accy += w * __uint_as_float(hw & 0xffff0000u);
        } else {
            float2 hv = *(const float2*)(H + (size_t)s * 128 + c);
            accx += w * hv.x;
            accy += w * hv.y;
        }
    }
    for (; i < deg; i++){                        // deg > CAP fallback
        int s = ep[i];
        float w = __expf(lrelu(asrc[s * 4 + hd] + adh) - mh);
        if (BF16){
            unsigned hw = Hb[(size_t)s * 64 + lane];
            accx += w * __uint_as_float(hw << 16);
            accy += w * __uint_as_float(hw & 0xffff0000u);
        } else {
            float2 hv = *(const float2*)(H + (size_t)s * 128 + c);
            accx += w * hv.x;
            accy += w * hv.y;
        }
    }
    accx *= rdh; accy *= rdh;

    if (!MEAN){
        float ox = elu_f(accx + bias[c]);
        float oy = elu_f(accy + bias[c + 1]);
        *(float2*)(Out + (size_t)n * 128 + c) = make_float2(ox, oy);
    } else {
        float sx = accx, sy = accy;
        sx += __shfl_xor(sx, 16); sy += __shfl_xor(sy, 16);
        sx += __shfl_xor(sx, 32); sy += __shfl_xor(sy, 32);
        if (lane < 16){
            int cc = lane * 2;
            float ox = elu_f(sx * 0.25f + bias[cc]);
            float oy = elu_f(sy * 0.25f + bias[cc + 1]);
            *(float2*)(Out + (size_t)n * 32 + cc) = make_float2(ox, oy);
        }
    }
}

// ---------------- readout ----------------

__global__ void k_readout(const float* __restrict__ H3, const int* __restrict__ batch,
                          const float* __restrict__ lw, const float* __restrict__ lb,
                          float* __restrict__ pool, float* __restrict__ cnt, int n_nodes){
    __shared__ float pl[64];
    __shared__ float cl[64];
    if (threadIdx.x < 64){ pl[threadIdx.x] = 0.f; cl[threadIdx.x] = 0.f; }
    __syncthreads();
    int n = blockIdx.x * 256 + threadIdx.x;
    if (n < n_nodes){
        const float4* hp = (const float4*)(H3 + (size_t)n * 32);
        const float4* wp = (const float4*)lw;
        float y = 0.f;
        #pragma unroll
        for (int i = 0; i < 8; i++){
            float4 h4 = hp[i], w4 = wp[i];
            y += h4.x * w4.x + h4.y * w4.y + h4.z * w4.z + h4.w * w4.w;
        }
        y += lb[0];
        int b = batch[n];
        atomicAdd(&pl[b], y);
        atomicAdd(&cl[b], 1.f);
    }
    __syncthreads();
    if (threadIdx.x < 64 && cl[threadIdx.x] != 0.f){
        atomicAdd(&pool[threadIdx.x], pl[threadIdx.x]);
        atomicAdd(&cnt[threadIdx.x], cl[threadIdx.x]);
    }
}

__global__ void k_final(const float* __restrict__ pool, const float* __restrict__ cnt,
                        float* __restrict__ out){
    int g = threadIdx.x;
    if (g < 64) out[g] = (cnt[g] > 0.f) ? pool[g] / cnt[g] : 0.f;
}

// ---------------- launch ----------------

extern "C" void kernel_launch(void* const* d_in, const int* in_sizes, int n_in,
                              void* d_out, int out_size, void* d_ws, size_t ws_size,
                              hipStream_t stream){
    const float* x   = (const float*)d_in[0];
    const int*   ei  = (const int*)  d_in[1];
    const int*   bat = (const int*)  d_in[2];
    const float* W1  = (const float*)d_in[3];
    const float* a1s = (const float*)d_in[4];
    const float* a1d = (const float*)d_in[5];
    const float* b1  = (const float*)d_in[6];
    const float* W2  = (const float*)d_in[7];
    const float* a2s = (const float*)d_in[8];
    const float* a2d = (const float*)d_in[9];
    const float* b2  = (const float*)d_in[10];
    const float* W3  = (const float*)d_in[11];
    const float* a3s = (const float*)d_in[12];
    const float* a3d = (const float*)d_in[13];
    const float* b3  = (const float*)d_in[14];
    const float* lw  = (const float*)d_in[15];
    const float* lb  = (const float*)d_in[16];
    (void)n_in; (void)out_size;

    const int n_nodes = in_sizes[0] / D1;      // 100000
    const int n_edges = in_sizes[1] / 2;       // 1600000
    const int etot    = n_edges + n_nodes;     // 1700000

    char* p = (char*)d_ws;
    size_t off = 0;
    auto alloc = [&](size_t bytes) -> char* {
        char* r = p + off;
        off = (off + bytes + 511) & ~(size_t)511;
        return r;
    };
    float* bufA   = (float*)alloc((size_t)n_nodes * D1 * 4);
    float* bufB   = (float*)alloc((size_t)n_nodes * D1 * 4);
    float* asrc   = (float*)alloc((size_t)n_nodes * 4 * 4);
    float* adst   = (float*)alloc((size_t)n_nodes * 4 * 4);
    float* WT     = (float*)alloc(3 * 128 * 128 * 4);
    int*   deg    = (int*)  alloc((size_t)n_nodes * 4);
    int*   rowptr = (int*)  alloc((size_t)(n_nodes + 1) * 4);
    int*   cursor = (int*)  alloc((size_t)n_nodes * 4);
    int*   bsum   = (int*)  alloc(4096);
    int*   eidx   = (int*)  alloc((size_t)etot * 4);
    float* pool   = (float*)alloc(64 * 4);
    float* cnt    = (float*)alloc(64 * 4);
    unsigned* bufAb = (unsigned*)alloc((size_t)n_nodes * 64 * 4);  // bf16 mirror, 25.6 MB
    bool use_bf16 = (off <= ws_size);
    if (!use_bf16) bufAb = nullptr;

    hipMemsetAsync(deg, 0, (size_t)n_nodes * 4, stream);
    hipMemsetAsync(pool, 0, 64 * 4, stream);
    hipMemsetAsync(cnt, 0, 64 * 4, stream);

    k_transw<<<192, 256, 0, stream>>>(W1, W2, W3, WT);

    int eb = (etot + 255) / 256;
    int nb = (n_nodes + 1023) / 1024;
    k_hist<<<eb, 256, 0, stream>>>(ei, deg, n_edges, etot);
    k_scan1<<<nb, 1024, 0, stream>>>(deg, rowptr, bsum, n_nodes);
    k_scan2<<<1, 64, 0, stream>>>(bsum, nb);
    k_scan3<<<nb, 1024, 0, stream>>>(rowptr, cursor, bsum, n_nodes, etot);
    k_scatter<<<eb, 256, 0, stream>>>(ei, cursor, eidx, n_edges, etot);

    int gb = (n_nodes + 63) / 64;
    int ab = (n_nodes * 4 + 255) / 256;
    int rb = (n_nodes + 3) / 4;

    // layer 1
    k_gemm<<<gb, 256, 0, stream>>>(x, WT, bufA, bufAb, n_nodes);
    k_att<<<ab, 256, 0, stream>>>(bufA, a1s, a1d, asrc, adst, n_nodes);
    if (use_bf16)
        k_aggr<0,1><<<rb, 256, 0, stream>>>(bufA, bufAb, asrc, adst, rowptr, eidx, b1, bufB, n_nodes);
    else
        k_aggr<0,0><<<rb, 256, 0, stream>>>(bufA, bufAb, asrc, adst, rowptr, eidx, b1, bufB, n_nodes);
    // layer 2
    k_gemm<<<gb, 256, 0, stream>>>(bufB, WT + 16384, bufA, bufAb, n_nodes);
    k_att<<<ab, 256, 0, stream>>>(bufA, a2s, a2d, asrc, adst, n_nodes);
    if (use_bf16)
        k_aggr<0,1><<<rb, 256, 0, stream>>>(bufA, bufAb, asrc, adst, rowptr, eidx, b2, bufB, n_nodes);
    else
        k_aggr<0,0><<<rb, 256, 0, stream>>>(bufA, bufAb, asrc, adst, rowptr, eidx, b2, bufB, n_nodes);
    // layer 3 (fp32 gather: last-layer bf16 noise would be too close to threshold)
    k_gemm<<<gb, 256, 0, stream>>>(bufB, WT + 32768, bufA, nullptr, n_nodes);
    k_att<<<ab, 256, 0, stream>>>(bufA, a3s, a3d, asrc, adst, n_nodes);
    k_aggr<1,0><<<rb, 256, 0, stream>>>(bufA, bufAb, asrc, adst, rowptr, eidx, b3, bufB, n_nodes);

    int ob = (n_nodes + 255) / 256;
    k_readout<<<ob, 256, 0, stream>>>(bufB, bat, lw, lb, pool, cnt, n_nodes);
    k_final<<<1, 64, 0, stream>>>(pool, cnt, (float*)d_out);
}

// Round 5
// 880.813 us; speedup vs baseline: 1.2433x; 1.2433x over previous
//
#include <hip/hip_runtime.h>
#include <math.h>

#define D1 128
#define NEG 0.2f

typedef short v8s __attribute__((ext_vector_type(8)));
typedef float v4f __attribute__((ext_vector_type(4)));

__device__ __forceinline__ float lrelu(float v){ return v > 0.f ? v : NEG * v; }
__device__ __forceinline__ float elu_f(float v){ return v > 0.f ? v : __expf(v) - 1.f; }

__device__ __forceinline__ unsigned short bf16s(float f){
    unsigned u = __float_as_uint(f);
    return (unsigned short)((u + 0x7fffu + ((u >> 16) & 1u)) >> 16);   // RNE
}
__device__ __forceinline__ float bf2f(unsigned short s){
    return __uint_as_float(((unsigned)s) << 16);
}

// ---------------- CSR build ----------------

__global__ void k_hist(const int* __restrict__ ei, int* __restrict__ deg,
                       int n_edges, int etot){
    int e = blockIdx.x * 256 + threadIdx.x;
    if (e >= etot) return;
    int dst = (e < n_edges) ? ei[n_edges + e] : (e - n_edges);
    atomicAdd(&deg[dst], 1);
}

__global__ __launch_bounds__(1024) void k_scan1(const int* __restrict__ deg,
                                                int* __restrict__ rowptr,
                                                int* __restrict__ bsum, int n){
    __shared__ int sd[1024];
    int i = blockIdx.x * 1024 + threadIdx.x;
    int v = (i < n) ? deg[i] : 0;
    sd[threadIdx.x] = v;
    __syncthreads();
    for (int off = 1; off < 1024; off <<= 1){
        int t = (threadIdx.x >= off) ? sd[threadIdx.x - off] : 0;
        __syncthreads();
        sd[threadIdx.x] += t;
        __syncthreads();
    }
    if (i < n) rowptr[i] = sd[threadIdx.x] - v;      // exclusive scan
    if (threadIdx.x == 1023) bsum[blockIdx.x] = sd[1023];
}

__global__ void k_scan2(int* bsum, int nb){
    if (threadIdx.x == 0){
        int run = 0;
        for (int b = 0; b < nb; b++){ int t = bsum[b]; bsum[b] = run; run += t; }
    }
}

__global__ __launch_bounds__(1024) void k_scan3(int* __restrict__ rowptr,
                                                int* __restrict__ cursor,
                                                const int* __restrict__ bsum,
                                                int n, int etot){
    int i = blockIdx.x * 1024 + threadIdx.x;
    if (i < n){
        int v = rowptr[i] + bsum[blockIdx.x];
        rowptr[i] = v;
        cursor[i] = v;
    }
    if (i == 0) rowptr[n] = etot;
}

__global__ void k_scatter(const int* __restrict__ ei, int* __restrict__ cursor,
                          int* __restrict__ eidx, int n_edges, int etot){
    int e = blockIdx.x * 256 + threadIdx.x;
    if (e >= etot) return;
    int src, dst;
    if (e < n_edges){ src = ei[e]; dst = ei[n_edges + e]; }
    else            { src = dst = e - n_edges; }
    int pos = atomicAdd(&cursor[dst], 1);
    eidx[pos] = src;
}

// ---------------- weight prep: split W into bf16 hi/lo, k-packed B' layout ----
// B[k][j] = W[j][k].  B'[kb][j][kk] with kb=k>>3, kk=k&7  (ushort).
// Per layer: hi block (16384) then lo block (16384). 3 layers.

__global__ void k_prepw(const float* __restrict__ W1, const float* __restrict__ W2,
                        const float* __restrict__ W3, unsigned short* __restrict__ Bp){
    int t = blockIdx.x * 256 + threadIdx.x;          // 0..49151
    if (t >= 49152) return;
    int w = t >> 14;
    int r = t & 16383;
    int k = r >> 7, j = r & 127;
    const float* W = (w == 0) ? W1 : (w == 1) ? W2 : W3;
    float val = W[j * 128 + k];
    unsigned short hi = bf16s(val);
    unsigned short lo = bf16s(val - bf2f(hi));
    int idx = (k >> 3) * 1024 + j * 8 + (k & 7);
    Bp[w * 32768 + idx] = hi;
    Bp[w * 32768 + 16384 + idx] = lo;
}

// ---------------- input split: fp32 -> bf16 hi/lo ----------------

__global__ void k_split(const float* __restrict__ X, unsigned short* __restrict__ Xhi,
                        unsigned short* __restrict__ Xlo, int nquads){
    int t = blockIdx.x * 256 + threadIdx.x;
    if (t >= nquads) return;
    float4 v = ((const float4*)X)[t];
    ushort4 hi, lo;
    hi.x = bf16s(v.x); lo.x = bf16s(v.x - bf2f(hi.x));
    hi.y = bf16s(v.y); lo.y = bf16s(v.y - bf2f(hi.y));
    hi.z = bf16s(v.z); lo.z = bf16s(v.z - bf2f(hi.z));
    hi.w = bf16s(v.w); lo.w = bf16s(v.w - bf2f(hi.w));
    ((ushort4*)Xhi)[t] = hi;
    ((ushort4*)Xlo)[t] = lo;
}

// ---------------- split-bf16 MFMA GEMM: H = X @ W.T ----------------
// H ~= Xhi@Bhi + Xhi@Blo + Xlo@Bhi  (fp32 acc, rel err ~2^-16)
// mfma_f32_16x16x32_bf16.  A: [m=lane&15][k=quad*8+j]; B: [k=quad*8+j][n=lane&15];
// C/D: [row=quad*4+reg][col=lane&15]  (guide-verified layouts, m89/m120).
// Wave = 32 rows (2 m-tiles) x 128 cols (8 n-tiles), K=128 in 4 steps.
// B frags read straight from global (64KB shared set -> L2-resident).

__global__ __launch_bounds__(256) void k_mgemm(const unsigned short* __restrict__ Xhi,
        const unsigned short* __restrict__ Xlo, const unsigned short* __restrict__ Bp,
        float* __restrict__ H, unsigned short* __restrict__ Hb, int n_rows){
    int lane = threadIdx.x & 63;
    int wv   = threadIdx.x >> 6;
    int li = lane & 15, quad = lane >> 4;
    int r0 = blockIdx.x * 128 + wv * 32;
    const unsigned short* bhi = Bp;
    const unsigned short* blo = Bp + 16384;

    v4f acc[2][8];
    #pragma unroll
    for (int m = 0; m < 2; m++)
        #pragma unroll
        for (int t = 0; t < 8; t++)
            acc[m][t] = (v4f){0.f, 0.f, 0.f, 0.f};

    int row0 = r0 + li;
    int row1 = r0 + 16 + li;
    int rc0 = row0 < n_rows ? row0 : 0;
    int rc1 = row1 < n_rows ? row1 : 0;

    #pragma unroll
    for (int ks = 0; ks < 4; ks++){
        int koff = ks * 32 + quad * 8;
        v8s ah0 = *(const v8s*)(Xhi + (size_t)rc0 * 128 + koff);
        v8s al0 = *(const v8s*)(Xlo + (size_t)rc0 * 128 + koff);
        v8s ah1 = *(const v8s*)(Xhi + (size_t)rc1 * 128 + koff);
        v8s al1 = *(const v8s*)(Xlo + (size_t)rc1 * 128 + koff);
        #pragma unroll
        for (int t = 0; t < 8; t++){
            int boff = ((ks * 4 + quad) * 128 + t * 16 + li) * 8;
            v8s bh = *(const v8s*)(bhi + boff);
            v8s bl = *(const v8s*)(blo + boff);
            acc[0][t] = __builtin_amdgcn_mfma_f32_16x16x32_bf16(ah0, bh, acc[0][t], 0, 0, 0);
            acc[0][t] = __builtin_amdgcn_mfma_f32_16x16x32_bf16(ah0, bl, acc[0][t], 0, 0, 0);
            acc[0][t] = __builtin_amdgcn_mfma_f32_16x16x32_bf16(al0, bh, acc[0][t], 0, 0, 0);
            acc[1][t] = __builtin_amdgcn_mfma_f32_16x16x32_bf16(ah1, bh, acc[1][t], 0, 0, 0);
            acc[1][t] = __builtin_amdgcn_mfma_f32_16x16x32_bf16(ah1, bl, acc[1][t], 0, 0, 0);
            acc[1][t] = __builtin_amdgcn_mfma_f32_16x16x32_bf16(al1, bh, acc[1][t], 0, 0, 0);
        }
    }

    #pragma unroll
    for (int m = 0; m < 2; m++){
        int rbase = r0 + m * 16 + quad * 4;
        #pragma unroll
        for (int r = 0; r < 4; r++){
            int row = rbase + r;
            if (row < n_rows){
                #pragma unroll
                for (int t = 0; t < 8; t++){
                    float v = acc[m][t][r];
                    H[(size_t)row * 128 + t * 16 + li] = v;
                    if (Hb) Hb[(size_t)row * 128 + t * 16 + li] = bf16s(v);
                }
            }
        }
    }
}

// ---------------- attention coefficients ----------------

__global__ void k_att(const float* __restrict__ H, const float* __restrict__ aw_s,
                      const float* __restrict__ aw_d, float* __restrict__ asrc,
                      float* __restrict__ adst, int n_nodes){
    int t = blockIdx.x * 256 + threadIdx.x;
    if (t >= n_nodes * 4) return;
    int n = t >> 2, hd = t & 3;
    const float4* hp = (const float4*)(H + (size_t)n * 128 + hd * 32);
    const float4* sp = (const float4*)(aw_s + hd * 32);
    const float4* dp = (const float4*)(aw_d + hd * 32);
    float s = 0.f, d = 0.f;
    #pragma unroll
    for (int i = 0; i < 8; i++){
        float4 h4 = hp[i], s4 = sp[i], d4 = dp[i];
        s += h4.x * s4.x + h4.y * s4.y + h4.z * s4.z + h4.w * s4.w;
        d += h4.x * d4.x + h4.y * d4.y + h4.z * d4.z + h4.w * d4.w;
    }
    asrc[t] = s;
    adst[t] = d;
}

// ---------------- softmax + aggregation, one wave per node ----------------
// BF16=1: gather from bf16 mirror; MEAN=0 writes bf16 hi/lo (next GEMM input),
// MEAN=1 writes fp32 [n][32] (readout input).

#define AGGR_CAP 96

template<int MEAN, int BF16>
__global__ __launch_bounds__(256) void k_aggr(const float* __restrict__ H,
        const unsigned* __restrict__ Hb,
        const float* __restrict__ asrc, const float* __restrict__ adst,
        const int* __restrict__ rowptr, const int* __restrict__ eidx,
        const float* __restrict__ bias,
        unsigned short* __restrict__ Oh, unsigned short* __restrict__ Ol,
        float* __restrict__ Of, int n_nodes){
    __shared__ float wls[4][AGGR_CAP * 4];     // 6 KB
    int lane = threadIdx.x & 63;
    int wid  = threadIdx.x >> 6;
    int n = blockIdx.x * 4 + wid;
    if (n >= n_nodes) return;
    int row0 = rowptr[n];
    int deg  = rowptr[n + 1] - row0;
    float4 ad = ((const float4*)adst)[n];
    float* wl = wls[wid];
    const int* ep = eidx + row0;

    // Phase A: edge scores (first strided round cached in regs) + max
    float e0 = -1e30f, e1 = -1e30f, e2 = -1e30f, e3 = -1e30f;
    if (lane < deg){
        int s = ep[lane];
        float4 av = ((const float4*)asrc)[s];
        e0 = lrelu(av.x + ad.x); e1 = lrelu(av.y + ad.y);
        e2 = lrelu(av.z + ad.z); e3 = lrelu(av.w + ad.w);
    }
    float m0 = e0, m1 = e1, m2 = e2, m3 = e3;
    for (int i = lane + 64; i < deg; i += 64){   // rare (deg > 64)
        int s = ep[i];
        float4 av = ((const float4*)asrc)[s];
        m0 = fmaxf(m0, lrelu(av.x + ad.x));
        m1 = fmaxf(m1, lrelu(av.y + ad.y));
        m2 = fmaxf(m2, lrelu(av.z + ad.z));
        m3 = fmaxf(m3, lrelu(av.w + ad.w));
    }
    #pragma unroll
    for (int off = 32; off; off >>= 1){
        m0 = fmaxf(m0, __shfl_xor(m0, off));
        m1 = fmaxf(m1, __shfl_xor(m1, off));
        m2 = fmaxf(m2, __shfl_xor(m2, off));
        m3 = fmaxf(m3, __shfl_xor(m3, off));
    }

    // Phase B: unnormalized exp -> LDS, accumulate denom
    float d0 = 0.f, d1 = 0.f, d2 = 0.f, d3 = 0.f;
    if (lane < deg){
        float x0 = __expf(e0 - m0), x1 = __expf(e1 - m1);
        float x2 = __expf(e2 - m2), x3 = __expf(e3 - m3);
        d0 = x0; d1 = x1; d2 = x2; d3 = x3;
        ((float4*)wl)[lane] = make_float4(x0, x1, x2, x3);
    }
    for (int i = lane + 64; i < deg; i += 64){   // rare
        int s = ep[i];
        float4 av = ((const float4*)asrc)[s];
        float x0 = __expf(lrelu(av.x + ad.x) - m0);
        float x1 = __expf(lrelu(av.y + ad.y) - m1);
        float x2 = __expf(lrelu(av.z + ad.z) - m2);
        float x3 = __expf(lrelu(av.w + ad.w) - m3);
        d0 += x0; d1 += x1; d2 += x2; d3 += x3;
        if (i < AGGR_CAP) ((float4*)wl)[i] = make_float4(x0, x1, x2, x3);
    }
    #pragma unroll
    for (int off = 32; off; off >>= 1){
        d0 += __shfl_xor(d0, off);
        d1 += __shfl_xor(d1, off);
        d2 += __shfl_xor(d2, off);
        d3 += __shfl_xor(d3, off);
    }
    int hd = lane >> 4;
    float mh  = hd == 0 ? m0 : hd == 1 ? m1 : hd == 2 ? m2 : m3;
    float rdh = 1.f / (hd == 0 ? d0 : hd == 1 ? d1 : hd == 2 ? d2 : d3);
    float adh = hd == 0 ? ad.x : hd == 1 ? ad.y : hd == 2 ? ad.z : ad.w;

    // Phase C: acc = sum_e w_e * h_e ; normalize once at the end
    float accx = 0.f, accy = 0.f;
    int c = lane * 2;
    const float* wlh = wl + hd;
    int cap = deg < AGGR_CAP ? deg : AGGR_CAP;
    int i = 0;
    for (; i + 8 <= cap; i += 8){
        int s[8];
        #pragma unroll
        for (int j = 0; j < 8; j++) s[j] = ep[i + j];
        if (BF16){
            unsigned hw[8];
            #pragma unroll
            for (int j = 0; j < 8; j++) hw[j] = Hb[(size_t)s[j] * 64 + lane];
            #pragma unroll
            for (int j = 0; j < 8; j++){
                float w = wlh[(i + j) * 4];
                accx += w * __uint_as_float(hw[j] << 16);
                accy += w * __uint_as_float(hw[j] & 0xffff0000u);
            }
        } else {
            float2 hv[8];
            #pragma unroll
            for (int j = 0; j < 8; j++) hv[j] = *(const float2*)(H + (size_t)s[j] * 128 + c);
            #pragma unroll
            for (int j = 0; j < 8; j++){
                float w = wlh[(i + j) * 4];
                accx += w * hv[j].x;
                accy += w * hv[j].y;
            }
        }
    }
    for (; i < cap; i++){
        int s = ep[i];
        float w = wlh[i * 4];
        if (BF16){
            unsigned hw = Hb[(size_t)s * 64 + lane];
            accx += w * __uint_as_float(hw << 16);
            accy += w * __uint_as_float(hw & 0xffff0000u);
        } else {
            float2 hv = *(const float2*)(H + (size_t)s * 128 + c);
            accx += w * hv.x;
            accy += w * hv.y;
        }
    }
    for (; i < deg; i++){                        // deg > CAP fallback
        int s = ep[i];
        float w = __expf(lrelu(asrc[s * 4 + hd] + adh) - mh);
        if (BF16){
            unsigned hw = Hb[(size_t)s * 64 + lane];
            accx += w * __uint_as_float(hw << 16);
            accy += w * __uint_as_float(hw & 0xffff0000u);
        } else {
            float2 hv = *(const float2*)(H + (size_t)s * 128 + c);
            accx += w * hv.x;
            accy += w * hv.y;
        }
    }
    accx *= rdh; accy *= rdh;

    if (!MEAN){
        float ox = elu_f(accx + bias[c]);
        float oy = elu_f(accy + bias[c + 1]);
        unsigned short hx = bf16s(ox), hy = bf16s(oy);
        unsigned short lx = bf16s(ox - bf2f(hx)), ly = bf16s(oy - bf2f(hy));
        *(ushort2*)(Oh + (size_t)n * 128 + c) = make_ushort2(hx, hy);
        *(ushort2*)(Ol + (size_t)n * 128 + c) = make_ushort2(lx, ly);
    } else {
        float sx = accx, sy = accy;
        sx += __shfl_xor(sx, 16); sy += __shfl_xor(sy, 16);
        sx += __shfl_xor(sx, 32); sy += __shfl_xor(sy, 32);
        if (lane < 16){
            int cc = lane * 2;
            float ox = elu_f(sx * 0.25f + bias[cc]);
            float oy = elu_f(sy * 0.25f + bias[cc + 1]);
            *(float2*)(Of + (size_t)n * 32 + cc) = make_float2(ox, oy);
        }
    }
}

// ---------------- readout ----------------

__global__ void k_readout(const float* __restrict__ H3, const int* __restrict__ batch,
                          const float* __restrict__ lw, const float* __restrict__ lb,
                          float* __restrict__ pool, float* __restrict__ cnt, int n_nodes){
    __shared__ float pl[64];
    __shared__ float cl[64];
    if (threadIdx.x < 64){ pl[threadIdx.x] = 0.f; cl[threadIdx.x] = 0.f; }
    __syncthreads();
    int n = blockIdx.x * 256 + threadIdx.x;
    if (n < n_nodes){
        const float4* hp = (const float4*)(H3 + (size_t)n * 32);
        const float4* wp = (const float4*)lw;
        float y = 0.f;
        #pragma unroll
        for (int i = 0; i < 8; i++){
            float4 h4 = hp[i], w4 = wp[i];
            y += h4.x * w4.x + h4.y * w4.y + h4.z * w4.z + h4.w * w4.w;
        }
        y += lb[0];
        int b = batch[n];
        atomicAdd(&pl[b], y);
        atomicAdd(&cl[b], 1.f);
    }
    __syncthreads();
    if (threadIdx.x < 64 && cl[threadIdx.x] != 0.f){
        atomicAdd(&pool[threadIdx.x], pl[threadIdx.x]);
        atomicAdd(&cnt[threadIdx.x], cl[threadIdx.x]);
    }
}

__global__ void k_final(const float* __restrict__ pool, const float* __restrict__ cnt,
                        float* __restrict__ out){
    int g = threadIdx.x;
    if (g < 64) out[g] = (cnt[g] > 0.f) ? pool[g] / cnt[g] : 0.f;
}

// ---------------- launch ----------------

extern "C" void kernel_launch(void* const* d_in, const int* in_sizes, int n_in,
                              void* d_out, int out_size, void* d_ws, size_t ws_size,
                              hipStream_t stream){
    const float* x   = (const float*)d_in[0];
    const int*   ei  = (const int*)  d_in[1];
    const int*   bat = (const int*)  d_in[2];
    const float* W1  = (const float*)d_in[3];
    const float* a1s = (const float*)d_in[4];
    const float* a1d = (const float*)d_in[5];
    const float* b1  = (const float*)d_in[6];
    const float* W2  = (const float*)d_in[7];
    const float* a2s = (const float*)d_in[8];
    const float* a2d = (const float*)d_in[9];
    const float* b2  = (const float*)d_in[10];
    const float* W3  = (const float*)d_in[11];
    const float* a3s = (const float*)d_in[12];
    const float* a3d = (const float*)d_in[13];
    const float* b3  = (const float*)d_in[14];
    const float* lw  = (const float*)d_in[15];
    const float* lb  = (const float*)d_in[16];
    (void)n_in; (void)out_size; (void)ws_size;

    const int n_nodes = in_sizes[0] / D1;      // 100000
    const int n_edges = in_sizes[1] / 2;       // 1600000
    const int etot    = n_edges + n_nodes;     // 1700000

    char* p = (char*)d_ws;
    size_t off = 0;
    auto alloc = [&](size_t bytes) -> char* {
        char* r = p + off;
        off = (off + bytes + 511) & ~(size_t)511;
        return r;
    };
    float*          H     = (float*)alloc((size_t)n_nodes * 128 * 4);          // 51.2 MB
    unsigned short* Hb16  = (unsigned short*)alloc((size_t)n_nodes * 128 * 2); // 25.6 MB
    unsigned short* Xhi   = (unsigned short*)alloc((size_t)n_nodes * 128 * 2); // 25.6 MB
    unsigned short* Xlo   = (unsigned short*)alloc((size_t)n_nodes * 128 * 2); // 25.6 MB
    float*          asrc  = (float*)alloc((size_t)n_nodes * 4 * 4);
    float*          adst  = (float*)alloc((size_t)n_nodes * 4 * 4);
    unsigned short* Bp    = (unsigned short*)alloc(3 * 32768 * 2);
    int*   deg    = (int*)alloc((size_t)n_nodes * 4);
    int*   rowptr = (int*)alloc((size_t)(n_nodes + 1) * 4);
    int*   cursor = (int*)alloc((size_t)n_nodes * 4);
    int*   bsum   = (int*)alloc(4096);
    int*   eidx   = (int*)alloc((size_t)etot * 4);
    float* pool   = (float*)alloc(64 * 4);
    float* cnt    = (float*)alloc(64 * 4);
    float* h3     = (float*)Hb16;              // alias: Hb unused in layer 3

    hipMemsetAsync(deg, 0, (size_t)n_nodes * 4, stream);
    hipMemsetAsync(pool, 0, 64 * 4, stream);
    hipMemsetAsync(cnt, 0, 64 * 4, stream);

    k_prepw<<<192, 256, 0, stream>>>(W1, W2, W3, Bp);

    int eb = (etot + 255) / 256;
    int nb = (n_nodes + 1023) / 1024;
    k_hist<<<eb, 256, 0, stream>>>(ei, deg, n_edges, etot);
    k_scan1<<<nb, 1024, 0, stream>>>(deg, rowptr, bsum, n_nodes);
    k_scan2<<<1, 64, 0, stream>>>(bsum, nb);
    k_scan3<<<nb, 1024, 0, stream>>>(rowptr, cursor, bsum, n_nodes, etot);
    k_scatter<<<eb, 256, 0, stream>>>(ei, cursor, eidx, n_edges, etot);

    int nquads = n_nodes * 32;                 // n*128/4
    k_split<<<(nquads + 255) / 256, 256, 0, stream>>>(x, Xhi, Xlo, nquads);

    int mb = (n_nodes + 127) / 128;
    int ab = (n_nodes * 4 + 255) / 256;
    int rb = (n_nodes + 3) / 4;

    // layer 1
    k_mgemm<<<mb, 256, 0, stream>>>(Xhi, Xlo, Bp, H, Hb16, n_nodes);
    k_att<<<ab, 256, 0, stream>>>(H, a1s, a1d, asrc, adst, n_nodes);
    k_aggr<0,1><<<rb, 256, 0, stream>>>(H, (const unsigned*)Hb16, asrc, adst,
                                        rowptr, eidx, b1, Xhi, Xlo, nullptr, n_nodes);
    // layer 2
    k_mgemm<<<mb, 256, 0, stream>>>(Xhi, Xlo, Bp + 32768, H, Hb16, n_nodes);
    k_att<<<ab, 256, 0, stream>>>(H, a2s, a2d, asrc, adst, n_nodes);
    k_aggr<0,1><<<rb, 256, 0, stream>>>(H, (const unsigned*)Hb16, asrc, adst,
                                        rowptr, eidx, b2, Xhi, Xlo, nullptr, n_nodes);
    // layer 3 (fp32 gather; output h3 aliased onto Hb region)
    k_mgemm<<<mb, 256, 0, stream>>>(Xhi, Xlo, Bp + 65536, H, nullptr, n_nodes);
    k_att<<<ab, 256, 0, stream>>>(H, a3s, a3d, asrc, adst, n_nodes);
    k_aggr<1,0><<<rb, 256, 0, stream>>>(H, nullptr, asrc, adst,
                                        rowptr, eidx, b3, nullptr, nullptr, h3, n_nodes);

    int ob = (n_nodes + 255) / 256;
    k_readout<<<ob, 256, 0, stream>>>(h3, bat, lw, lb, pool, cnt, n_nodes);
    k_final<<<1, 64, 0, stream>>>(pool, cnt, (float*)d_out);
}

// Round 6
// 769.418 us; speedup vs baseline: 1.4233x; 1.1448x over previous
//
#include <hip/hip_runtime.h>
#include <hip/hip_fp16.h>
#include <math.h>

#define D1 128
#define NEG 0.2f

typedef short v8s __attribute__((ext_vector_type(8)));
typedef float v4f __attribute__((ext_vector_type(4)));

__device__ __forceinline__ float lrelu(float v){ return v > 0.f ? v : NEG * v; }
__device__ __forceinline__ float elu_f(float v){ return v > 0.f ? v : __expf(v) - 1.f; }

__device__ __forceinline__ unsigned short bf16s(float f){
    unsigned u = __float_as_uint(f);
    return (unsigned short)((u + 0x7fffu + ((u >> 16) & 1u)) >> 16);   // RNE
}
__device__ __forceinline__ float bf2f(unsigned short s){
    return __uint_as_float(((unsigned)s) << 16);
}
__device__ __forceinline__ unsigned f2h2(float a, float b){           // a->low, b->high
    return ((unsigned)__half_as_ushort(__float2half_rn(b)) << 16) |
           (unsigned)__half_as_ushort(__float2half_rn(a));
}
__device__ __forceinline__ float2 h2f2(unsigned u){
    float lo = __half2float(__ushort_as_half((unsigned short)(u & 0xffffu)));
    float hi = __half2float(__ushort_as_half((unsigned short)(u >> 16)));
    return make_float2(lo, hi);
}

// ---------------- CSR build ----------------

__global__ void k_hist(const int* __restrict__ ei, int* __restrict__ deg,
                       int n_edges, int etot){
    int e = blockIdx.x * 256 + threadIdx.x;
    if (e >= etot) return;
    int dst = (e < n_edges) ? ei[n_edges + e] : (e - n_edges);
    atomicAdd(&deg[dst], 1);
}

__global__ __launch_bounds__(1024) void k_scan1(const int* __restrict__ deg,
                                                int* __restrict__ rowptr,
                                                int* __restrict__ bsum, int n){
    __shared__ int sd[1024];
    int i = blockIdx.x * 1024 + threadIdx.x;
    int v = (i < n) ? deg[i] : 0;
    sd[threadIdx.x] = v;
    __syncthreads();
    for (int off = 1; off < 1024; off <<= 1){
        int t = (threadIdx.x >= off) ? sd[threadIdx.x - off] : 0;
        __syncthreads();
        sd[threadIdx.x] += t;
        __syncthreads();
    }
    if (i < n) rowptr[i] = sd[threadIdx.x] - v;      // exclusive scan
    if (threadIdx.x == 1023) bsum[blockIdx.x] = sd[1023];
}

__global__ void k_scan2(int* bsum, int nb){
    if (threadIdx.x == 0){
        int run = 0;
        for (int b = 0; b < nb; b++){ int t = bsum[b]; bsum[b] = run; run += t; }
    }
}

__global__ __launch_bounds__(1024) void k_scan3(int* __restrict__ rowptr,
                                                int* __restrict__ cursor,
                                                const int* __restrict__ bsum,
                                                int n, int etot){
    int i = blockIdx.x * 1024 + threadIdx.x;
    if (i < n){
        int v = rowptr[i] + bsum[blockIdx.x];
        rowptr[i] = v;
        cursor[i] = v;
    }
    if (i == 0) rowptr[n] = etot;
}

__global__ void k_scatter(const int* __restrict__ ei, int* __restrict__ cursor,
                          int* __restrict__ eidx, int n_edges, int etot){
    int e = blockIdx.x * 256 + threadIdx.x;
    if (e >= etot) return;
    int src, dst;
    if (e < n_edges){ src = ei[e]; dst = ei[n_edges + e]; }
    else            { src = dst = e - n_edges; }
    int pos = atomicAdd(&cursor[dst], 1);
    eidx[pos] = src;
}

// ---------------- weight prep: split W into bf16 hi/lo, k-packed B' layout ----
// B[k][j] = W[j][k].  B'[kb][j][kk] with kb=k>>3, kk=k&7 (ushort).
// Per layer: hi block (16384) then lo block (16384). 3 layers.

__global__ void k_prepw(const float* __restrict__ W1, const float* __restrict__ W2,
                        const float* __restrict__ W3, unsigned short* __restrict__ Bp){
    int t = blockIdx.x * 256 + threadIdx.x;          // 0..49151
    if (t >= 49152) return;
    int w = t >> 14;
    int r = t & 16383;
    int k = r >> 7, j = r & 127;
    const float* W = (w == 0) ? W1 : (w == 1) ? W2 : W3;
    float val = W[j * 128 + k];
    unsigned short hi = bf16s(val);
    unsigned short lo = bf16s(val - bf2f(hi));
    int idx = (k >> 3) * 1024 + j * 8 + (k & 7);
    Bp[w * 32768 + idx] = hi;
    Bp[w * 32768 + 16384 + idx] = lo;
}

// ---------------- input split: fp32 -> bf16 hi/lo ----------------

__global__ void k_split(const float* __restrict__ X, unsigned short* __restrict__ Xhi,
                        unsigned short* __restrict__ Xlo, int nquads){
    int t = blockIdx.x * 256 + threadIdx.x;
    if (t >= nquads) return;
    float4 v = ((const float4*)X)[t];
    ushort4 hi, lo;
    hi.x = bf16s(v.x); lo.x = bf16s(v.x - bf2f(hi.x));
    hi.y = bf16s(v.y); lo.y = bf16s(v.y - bf2f(hi.y));
    hi.z = bf16s(v.z); lo.z = bf16s(v.z - bf2f(hi.z));
    hi.w = bf16s(v.w); lo.w = bf16s(v.w - bf2f(hi.w));
    ((ushort4*)Xhi)[t] = hi;
    ((ushort4*)Xlo)[t] = lo;
}

// ---------------- split-bf16 MFMA GEMM + fused attention coefficients --------
// H ~= Xhi@Bhi + Xhi@Blo + Xlo@Bhi (fp32 acc). B staged per-K-slice in LDS.
// Outputs: fp16 mirror Hh[n][128], asrc[n][4], adst[n][4]. No fp32 H buffer.
// mfma_f32_16x16x32_bf16: A[m=lane&15][k=quad*8+j]; C/D[row=quad*4+reg][col=lane&15].

__global__ __launch_bounds__(256) void k_mgemm(
        const unsigned short* __restrict__ Xhi, const unsigned short* __restrict__ Xlo,
        const unsigned short* __restrict__ Bp,
        const float* __restrict__ aw_s, const float* __restrict__ aw_d,
        unsigned short* __restrict__ Hh,
        float* __restrict__ asrc, float* __restrict__ adst, int n_rows){
    __shared__ unsigned short Bs[8192];          // 16 KB: hi[4096] + lo[4096], one K-slice
    int lane = threadIdx.x & 63;
    int wv   = threadIdx.x >> 6;
    int li = lane & 15, quad = lane >> 4;
    int r0 = blockIdx.x * 128 + wv * 32;

    int row0 = r0 + li;
    int row1 = r0 + 16 + li;
    int rc0 = row0 < n_rows ? row0 : 0;
    int rc1 = row1 < n_rows ? row1 : 0;

    // hoist all A fragment loads (16 x 16B global loads, issued up-front)
    v8s ah0[4], al0[4], ah1[4], al1[4];
    #pragma unroll
    for (int ks = 0; ks < 4; ks++){
        int koff = ks * 32 + quad * 8;
        ah0[ks] = *(const v8s*)(Xhi + (size_t)rc0 * 128 + koff);
        al0[ks] = *(const v8s*)(Xlo + (size_t)rc0 * 128 + koff);
        ah1[ks] = *(const v8s*)(Xhi + (size_t)rc1 * 128 + koff);
        al1[ks] = *(const v8s*)(Xlo + (size_t)rc1 * 128 + koff);
    }

    v4f acc[2][8];
    #pragma unroll
    for (int m = 0; m < 2; m++)
        #pragma unroll
        for (int t = 0; t < 8; t++)
            acc[m][t] = (v4f){0.f, 0.f, 0.f, 0.f};

    #pragma unroll
    for (int ks = 0; ks < 4; ks++){
        if (ks) __syncthreads();
        #pragma unroll
        for (int i = 0; i < 2; i++){
            int idx = threadIdx.x + i * 256;
            ((float4*)Bs)[idx]          = ((const float4*)(Bp + ks * 4096))[idx];
            ((float4*)(Bs + 4096))[idx] = ((const float4*)(Bp + 16384 + ks * 4096))[idx];
        }
        __syncthreads();
        #pragma unroll
        for (int t = 0; t < 8; t++){
            int bo = quad * 1024 + (t * 16 + li) * 8;
            v8s bh = *(const v8s*)(Bs + bo);
            v8s bl = *(const v8s*)(Bs + 4096 + bo);
            acc[0][t] = __builtin_amdgcn_mfma_f32_16x16x32_bf16(ah0[ks], bh, acc[0][t], 0, 0, 0);
            acc[0][t] = __builtin_amdgcn_mfma_f32_16x16x32_bf16(ah0[ks], bl, acc[0][t], 0, 0, 0);
            acc[0][t] = __builtin_amdgcn_mfma_f32_16x16x32_bf16(al0[ks], bh, acc[0][t], 0, 0, 0);
            acc[1][t] = __builtin_amdgcn_mfma_f32_16x16x32_bf16(ah1[ks], bh, acc[1][t], 0, 0, 0);
            acc[1][t] = __builtin_amdgcn_mfma_f32_16x16x32_bf16(ah1[ks], bl, acc[1][t], 0, 0, 0);
            acc[1][t] = __builtin_amdgcn_mfma_f32_16x16x32_bf16(al1[ks], bh, acc[1][t], 0, 0, 0);
        }
    }

    // ---- epilogue 1: fp16 mirror (pack adjacent cols via lane-xor) ----
    #pragma unroll
    for (int m = 0; m < 2; m++){
        #pragma unroll
        for (int t = 0; t < 8; t++){
            #pragma unroll
            for (int r = 0; r < 4; r++){
                float v  = acc[m][t][r];
                float vo = __shfl_xor(v, 1);
                if (!(li & 1)){
                    int row = r0 + m * 16 + quad * 4 + r;
                    if (row < n_rows)
                        *(unsigned*)(Hh + (size_t)row * 128 + t * 16 + li) = f2h2(v, vo);
                }
            }
        }
    }

    // ---- epilogue 2: fused attention coefficients (fp32, full precision) ----
    float as8[8], ad8[8];
    #pragma unroll
    for (int t = 0; t < 8; t++){
        as8[t] = aw_s[t * 16 + li];
        ad8[t] = aw_d[t * 16 + li];
    }
    #pragma unroll
    for (int m = 0; m < 2; m++){
        #pragma unroll
        for (int r = 0; r < 4; r++){
            float sp[4], dp[4];
            #pragma unroll
            for (int h = 0; h < 4; h++){
                sp[h] = acc[m][2*h][r] * as8[2*h] + acc[m][2*h+1][r] * as8[2*h+1];
                dp[h] = acc[m][2*h][r] * ad8[2*h] + acc[m][2*h+1][r] * ad8[2*h+1];
            }
            #pragma unroll
            for (int off = 1; off < 16; off <<= 1){
                #pragma unroll
                for (int h = 0; h < 4; h++){
                    sp[h] += __shfl_xor(sp[h], off);
                    dp[h] += __shfl_xor(dp[h], off);
                }
            }
            if (li == 0){
                int row = r0 + m * 16 + quad * 4 + r;
                if (row < n_rows){
                    ((float4*)asrc)[row] = make_float4(sp[0], sp[1], sp[2], sp[3]);
                    ((float4*)adst)[row] = make_float4(dp[0], dp[1], dp[2], dp[3]);
                }
            }
        }
    }
}

// ---------------- softmax + aggregation, one wave per node ----------------
// Gathers the fp16 mirror (4 B/lane/edge). MEAN=0 writes bf16 hi/lo (next GEMM
// input); MEAN=1 writes fp32 [n][32] (readout input).

#define AGGR_CAP 96

template<int MEAN>
__global__ __launch_bounds__(256) void k_aggr(
        const unsigned* __restrict__ Hh,
        const float* __restrict__ asrc, const float* __restrict__ adst,
        const int* __restrict__ rowptr, const int* __restrict__ eidx,
        const float* __restrict__ bias,
        unsigned short* __restrict__ Oh, unsigned short* __restrict__ Ol,
        float* __restrict__ Of, int n_nodes){
    __shared__ float wls[4][AGGR_CAP * 4];     // 6 KB
    int lane = threadIdx.x & 63;
    int wid  = threadIdx.x >> 6;
    int n = blockIdx.x * 4 + wid;
    if (n >= n_nodes) return;
    int row0 = rowptr[n];
    int deg  = rowptr[n + 1] - row0;
    float4 ad = ((const float4*)adst)[n];
    float* wl = wls[wid];
    const int* ep = eidx + row0;

    // Phase A: edge scores (first strided round cached in regs) + max
    float e0 = -1e30f, e1 = -1e30f, e2 = -1e30f, e3 = -1e30f;
    if (lane < deg){
        int s = ep[lane];
        float4 av = ((const float4*)asrc)[s];
        e0 = lrelu(av.x + ad.x); e1 = lrelu(av.y + ad.y);
        e2 = lrelu(av.z + ad.z); e3 = lrelu(av.w + ad.w);
    }
    float m0 = e0, m1 = e1, m2 = e2, m3 = e3;
    for (int i = lane + 64; i < deg; i += 64){   // rare (deg > 64)
        int s = ep[i];
        float4 av = ((const float4*)asrc)[s];
        m0 = fmaxf(m0, lrelu(av.x + ad.x));
        m1 = fmaxf(m1, lrelu(av.y + ad.y));
        m2 = fmaxf(m2, lrelu(av.z + ad.z));
        m3 = fmaxf(m3, lrelu(av.w + ad.w));
    }
    #pragma unroll
    for (int off = 32; off; off >>= 1){
        m0 = fmaxf(m0, __shfl_xor(m0, off));
        m1 = fmaxf(m1, __shfl_xor(m1, off));
        m2 = fmaxf(m2, __shfl_xor(m2, off));
        m3 = fmaxf(m3, __shfl_xor(m3, off));
    }

    // Phase B: unnormalized exp -> LDS, accumulate denom
    float d0 = 0.f, d1 = 0.f, d2 = 0.f, d3 = 0.f;
    if (lane < deg){
        float x0 = __expf(e0 - m0), x1 = __expf(e1 - m1);
        float x2 = __expf(e2 - m2), x3 = __expf(e3 - m3);
        d0 = x0; d1 = x1; d2 = x2; d3 = x3;
        ((float4*)wl)[lane] = make_float4(x0, x1, x2, x3);
    }
    for (int i = lane + 64; i < deg; i += 64){   // rare
        int s = ep[i];
        float4 av = ((const float4*)asrc)[s];
        float x0 = __expf(lrelu(av.x + ad.x) - m0);
        float x1 = __expf(lrelu(av.y + ad.y) - m1);
        float x2 = __expf(lrelu(av.z + ad.z) - m2);
        float x3 = __expf(lrelu(av.w + ad.w) - m3);
        d0 += x0; d1 += x1; d2 += x2; d3 += x3;
        if (i < AGGR_CAP) ((float4*)wl)[i] = make_float4(x0, x1, x2, x3);
    }
    #pragma unroll
    for (int off = 32; off; off >>= 1){
        d0 += __shfl_xor(d0, off);
        d1 += __shfl_xor(d1, off);
        d2 += __shfl_xor(d2, off);
        d3 += __shfl_xor(d3, off);
    }
    int hd = lane >> 4;
    float mh  = hd == 0 ? m0 : hd == 1 ? m1 : hd == 2 ? m2 : m3;
    float rdh = 1.f / (hd == 0 ? d0 : hd == 1 ? d1 : hd == 2 ? d2 : d3);
    float adh = hd == 0 ? ad.x : hd == 1 ? ad.y : hd == 2 ? ad.z : ad.w;

    // Phase C: acc = sum_e w_e * h_e (fp16 gather); normalize at the end
    float accx = 0.f, accy = 0.f;
    int c = lane * 2;
    const float* wlh = wl + hd;
    int cap = deg < AGGR_CAP ? deg : AGGR_CAP;
    int i = 0;
    for (; i + 8 <= cap; i += 8){
        int s[8];
        #pragma unroll
        for (int j = 0; j < 8; j++) s[j] = ep[i + j];
        unsigned hw[8];
        #pragma unroll
        for (int j = 0; j < 8; j++) hw[j] = Hh[(size_t)s[j] * 64 + lane];
        #pragma unroll
        for (int j = 0; j < 8; j++){
            float w = wlh[(i + j) * 4];
            float2 hv = h2f2(hw[j]);
            accx += w * hv.x;
            accy += w * hv.y;
        }
    }
    for (; i < cap; i++){
        int s = ep[i];
        float w = wlh[i * 4];
        float2 hv = h2f2(Hh[(size_t)s * 64 + lane]);
        accx += w * hv.x;
        accy += w * hv.y;
    }
    for (; i < deg; i++){                        // deg > CAP fallback
        int s = ep[i];
        float w = __expf(lrelu(asrc[s * 4 + hd] + adh) - mh);
        float2 hv = h2f2(Hh[(size_t)s * 64 + lane]);
        accx += w * hv.x;
        accy += w * hv.y;
    }
    accx *= rdh; accy *= rdh;

    if (!MEAN){
        float ox = elu_f(accx + bias[c]);
        float oy = elu_f(accy + bias[c + 1]);
        unsigned short hx = bf16s(ox), hy = bf16s(oy);
        unsigned short lx = bf16s(ox - bf2f(hx)), ly = bf16s(oy - bf2f(hy));
        *(ushort2*)(Oh + (size_t)n * 128 + c) = make_ushort2(hx, hy);
        *(ushort2*)(Ol + (size_t)n * 128 + c) = make_ushort2(lx, ly);
    } else {
        float sx = accx, sy = accy;
        sx += __shfl_xor(sx, 16); sy += __shfl_xor(sy, 16);
        sx += __shfl_xor(sx, 32); sy += __shfl_xor(sy, 32);
        if (lane < 16){
            int cc = lane * 2;
            float ox = elu_f(sx * 0.25f + bias[cc]);
            float oy = elu_f(sy * 0.25f + bias[cc + 1]);
            *(float2*)(Of + (size_t)n * 32 + cc) = make_float2(ox, oy);
        }
    }
}

// ---------------- readout ----------------

__global__ void k_readout(const float* __restrict__ H3, const int* __restrict__ batch,
                          const float* __restrict__ lw, const float* __restrict__ lb,
                          float* __restrict__ pool, float* __restrict__ cnt, int n_nodes){
    __shared__ float pl[64];
    __shared__ float cl[64];
    if (threadIdx.x < 64){ pl[threadIdx.x] = 0.f; cl[threadIdx.x] = 0.f; }
    __syncthreads();
    int n = blockIdx.x * 256 + threadIdx.x;
    if (n < n_nodes){
        const float4* hp = (const float4*)(H3 + (size_t)n * 32);
        const float4* wp = (const float4*)lw;
        float y = 0.f;
        #pragma unroll
        for (int i = 0; i < 8; i++){
            float4 h4 = hp[i], w4 = wp[i];
            y += h4.x * w4.x + h4.y * w4.y + h4.z * w4.z + h4.w * w4.w;
        }
        y += lb[0];
        int b = batch[n];
        atomicAdd(&pl[b], y);
        atomicAdd(&cl[b], 1.f);
    }
    __syncthreads();
    if (threadIdx.x < 64 && cl[threadIdx.x] != 0.f){
        atomicAdd(&pool[threadIdx.x], pl[threadIdx.x]);
        atomicAdd(&cnt[threadIdx.x], cl[threadIdx.x]);
    }
}

__global__ void k_final(const float* __restrict__ pool, const float* __restrict__ cnt,
                        float* __restrict__ out){
    int g = threadIdx.x;
    if (g < 64) out[g] = (cnt[g] > 0.f) ? pool[g] / cnt[g] : 0.f;
}

// ---------------- launch ----------------

extern "C" void kernel_launch(void* const* d_in, const int* in_sizes, int n_in,
                              void* d_out, int out_size, void* d_ws, size_t ws_size,
                              hipStream_t stream){
    const float* x   = (const float*)d_in[0];
    const int*   ei  = (const int*)  d_in[1];
    const int*   bat = (const int*)  d_in[2];
    const float* W1  = (const float*)d_in[3];
    const float* a1s = (const float*)d_in[4];
    const float* a1d = (const float*)d_in[5];
    const float* b1  = (const float*)d_in[6];
    const float* W2  = (const float*)d_in[7];
    const float* a2s = (const float*)d_in[8];
    const float* a2d = (const float*)d_in[9];
    const float* b2  = (const float*)d_in[10];
    const float* W3  = (const float*)d_in[11];
    const float* a3s = (const float*)d_in[12];
    const float* a3d = (const float*)d_in[13];
    const float* b3  = (const float*)d_in[14];
    const float* lw  = (const float*)d_in[15];
    const float* lb  = (const float*)d_in[16];
    (void)n_in; (void)out_size; (void)ws_size;

    const int n_nodes = in_sizes[0] / D1;      // 100000
    const int n_edges = in_sizes[1] / 2;       // 1600000
    const int etot    = n_edges + n_nodes;     // 1700000

    char* p = (char*)d_ws;
    size_t off = 0;
    auto alloc = [&](size_t bytes) -> char* {
        char* r = p + off;
        off = (off + bytes + 511) & ~(size_t)511;
        return r;
    };
    unsigned short* Hh   = (unsigned short*)alloc((size_t)n_nodes * 128 * 2); // 25.6 MB fp16 mirror
    unsigned short* Xhi  = (unsigned short*)alloc((size_t)n_nodes * 128 * 2); // 25.6 MB
    unsigned short* Xlo  = (unsigned short*)alloc((size_t)n_nodes * 128 * 2); // 25.6 MB
    float*          asrc = (float*)alloc((size_t)n_nodes * 4 * 4);
    float*          adst = (float*)alloc((size_t)n_nodes * 4 * 4);
    unsigned short* Bp   = (unsigned short*)alloc(3 * 32768 * 2);
    int*   deg    = (int*)alloc((size_t)n_nodes * 4);
    int*   rowptr = (int*)alloc((size_t)(n_nodes + 1) * 4);
    int*   cursor = (int*)alloc((size_t)n_nodes * 4);
    int*   bsum   = (int*)alloc(4096);
    int*   eidx   = (int*)alloc((size_t)etot * 4);
    float* pool   = (float*)alloc(64 * 4);
    float* cnt    = (float*)alloc(64 * 4);
    float* h3     = (float*)Xhi;               // alias: Xhi not read by layer-3 aggr

    hipMemsetAsync(deg, 0, (size_t)n_nodes * 4, stream);
    hipMemsetAsync(pool, 0, 64 * 4, stream);
    hipMemsetAsync(cnt, 0, 64 * 4, stream);

    k_prepw<<<192, 256, 0, stream>>>(W1, W2, W3, Bp);

    int eb = (etot + 255) / 256;
    int nb = (n_nodes + 1023) / 1024;
    k_hist<<<eb, 256, 0, stream>>>(ei, deg, n_edges, etot);
    k_scan1<<<nb, 1024, 0, stream>>>(deg, rowptr, bsum, n_nodes);
    k_scan2<<<1, 64, 0, stream>>>(bsum, nb);
    k_scan3<<<nb, 1024, 0, stream>>>(rowptr, cursor, bsum, n_nodes, etot);
    k_scatter<<<eb, 256, 0, stream>>>(ei, cursor, eidx, n_edges, etot);

    int nquads = n_nodes * 32;                 // n*128/4
    k_split<<<(nquads + 255) / 256, 256, 0, stream>>>(x, Xhi, Xlo, nquads);

    int mb = (n_nodes + 127) / 128;
    int rb = (n_nodes + 3) / 4;

    // layer 1
    k_mgemm<<<mb, 256, 0, stream>>>(Xhi, Xlo, Bp, a1s, a1d, Hh, asrc, adst, n_nodes);
    k_aggr<0><<<rb, 256, 0, stream>>>((const unsigned*)Hh, asrc, adst, rowptr, eidx,
                                      b1, Xhi, Xlo, nullptr, n_nodes);
    // layer 2
    k_mgemm<<<mb, 256, 0, stream>>>(Xhi, Xlo, Bp + 32768, a2s, a2d, Hh, asrc, adst, n_nodes);
    k_aggr<0><<<rb, 256, 0, stream>>>((const unsigned*)Hh, asrc, adst, rowptr, eidx,
                                      b2, Xhi, Xlo, nullptr, n_nodes);
    // layer 3 (fp16 gather; h3 fp32 aliased onto Xhi)
    k_mgemm<<<mb, 256, 0, stream>>>(Xhi, Xlo, Bp + 65536, a3s, a3d, Hh, asrc, adst, n_nodes);
    k_aggr<1><<<rb, 256, 0, stream>>>((const unsigned*)Hh, asrc, adst, rowptr, eidx,
                                      b3, nullptr, nullptr, h3, n_nodes);

    int ob = (n_nodes + 255) / 256;
    k_readout<<<ob, 256, 0, stream>>>(h3, bat, lw, lb, pool, cnt, n_nodes);
    k_final<<<1, 64, 0, stream>>>(pool, cnt, (float*)d_out);
}

// Round 7
// 624.821 us; speedup vs baseline: 1.7527x; 1.2314x over previous
//
#include <hip/hip_runtime.h>
#include <hip/hip_fp16.h>
#include <math.h>

#define D1 128
#define NEG 0.2f
#define NODE_SHIFT 9
#define BIN_NODES 512
#define MAXBIN 256

typedef short v8s __attribute__((ext_vector_type(8)));
typedef float v4f __attribute__((ext_vector_type(4)));

__device__ __forceinline__ float lrelu(float v){ return v > 0.f ? v : NEG * v; }
__device__ __forceinline__ float elu_f(float v){ return v > 0.f ? v : __expf(v) - 1.f; }

__device__ __forceinline__ unsigned short bf16s(float f){
    unsigned u = __float_as_uint(f);
    return (unsigned short)((u + 0x7fffu + ((u >> 16) & 1u)) >> 16);   // RNE
}
__device__ __forceinline__ float bf2f(unsigned short s){
    return __uint_as_float(((unsigned)s) << 16);
}
__device__ __forceinline__ unsigned f2h2(float a, float b){           // a->low, b->high
    return ((unsigned)__half_as_ushort(__float2half_rn(b)) << 16) |
           (unsigned)__half_as_ushort(__float2half_rn(a));
}
__device__ __forceinline__ float2 h2f2(unsigned u){
    float lo = __half2float(__ushort_as_half((unsigned short)(u & 0xffffu)));
    float hi = __half2float(__ushort_as_half((unsigned short)(u >> 16)));
    return make_float2(lo, hi);
}

// ---------------- binned CSR build ----------------
// bin = dst >> 9 (512 nodes/bin). Global atomics only on per-bin counters;
// per-node degree/cursor work happens in LDS inside one block per bin.

__global__ __launch_bounds__(256) void kb_hist(const int* __restrict__ ei,
                                               int* __restrict__ binCnt,
                                               int n_edges, int etot, int nbin){
    __shared__ int h[MAXBIN];
    for (int i = threadIdx.x; i < nbin; i += 256) h[i] = 0;
    __syncthreads();
    int stride = gridDim.x * 256;
    for (int e = blockIdx.x * 256 + threadIdx.x; e < etot; e += stride){
        int dst = (e < n_edges) ? ei[n_edges + e] : (e - n_edges);
        atomicAdd(&h[dst >> NODE_SHIFT], 1);
    }
    __syncthreads();
    for (int i = threadIdx.x; i < nbin; i += 256)
        if (h[i]) atomicAdd(&binCnt[i], h[i]);
}

__global__ void kb_scan(const int* __restrict__ binCnt, int* __restrict__ binStart,
                        int* __restrict__ binCursor, int nbin,
                        int* __restrict__ rowptr, int n_nodes, int etot){
    if (threadIdx.x == 0){
        int run = 0;
        for (int b = 0; b < nbin; b++){
            binStart[b] = run; binCursor[b] = run; run += binCnt[b];
        }
        binStart[nbin] = run;
        rowptr[n_nodes] = etot;
    }
}

__global__ __launch_bounds__(256) void kb_scatter(const int* __restrict__ ei,
                                                  int* __restrict__ binCursor,
                                                  uint2* __restrict__ staged,
                                                  int n_edges, int etot, int nbin){
    __shared__ int cnt[MAXBIN];
    __shared__ int base[MAXBIN];
    int e0 = blockIdx.x * 4096;
    for (int i = threadIdx.x; i < nbin; i += 256) cnt[i] = 0;
    __syncthreads();
    #pragma unroll 4
    for (int r = 0; r < 16; r++){
        int e = e0 + r * 256 + threadIdx.x;
        if (e < etot){
            int dst = (e < n_edges) ? ei[n_edges + e] : (e - n_edges);
            atomicAdd(&cnt[dst >> NODE_SHIFT], 1);
        }
    }
    __syncthreads();
    for (int i = threadIdx.x; i < nbin; i += 256){
        base[i] = cnt[i] ? atomicAdd(&binCursor[i], cnt[i]) : 0;
        cnt[i] = 0;
    }
    __syncthreads();
    #pragma unroll 4
    for (int r = 0; r < 16; r++){
        int e = e0 + r * 256 + threadIdx.x;
        if (e < etot){
            int src, dst;
            if (e < n_edges){ src = ei[e]; dst = ei[n_edges + e]; }
            else            { src = dst = e - n_edges; }
            int b = dst >> NODE_SHIFT;
            int p = base[b] + atomicAdd(&cnt[b], 1);
            staged[p] = make_uint2((unsigned)src, (unsigned)dst);
        }
    }
}

__global__ __launch_bounds__(512) void kb_final(const uint2* __restrict__ staged,
                                                const int* __restrict__ binStart,
                                                int* __restrict__ rowptr,
                                                int* __restrict__ eidx, int n_nodes){
    __shared__ int deg[BIN_NODES];
    __shared__ int cur[BIN_NODES];
    int b = blockIdx.x;
    int nbase = b << NODE_SHIFT;
    int s0 = binStart[b], s1 = binStart[b + 1];
    deg[threadIdx.x] = 0;
    __syncthreads();
    for (int i = s0 + threadIdx.x; i < s1; i += 512)
        atomicAdd(&deg[staged[i].y & (BIN_NODES - 1)], 1);
    __syncthreads();
    int v = deg[threadIdx.x];
    cur[threadIdx.x] = v;
    __syncthreads();
    for (int off = 1; off < BIN_NODES; off <<= 1){
        int t = (threadIdx.x >= off) ? cur[threadIdx.x - off] : 0;
        __syncthreads();
        cur[threadIdx.x] += t;
        __syncthreads();
    }
    int excl = cur[threadIdx.x] - v;           // exclusive prefix within bin
    int node = nbase + threadIdx.x;
    if (node < n_nodes) rowptr[node] = s0 + excl;
    cur[threadIdx.x] = s0 + excl;              // becomes cursor
    __syncthreads();
    for (int i = s0 + threadIdx.x; i < s1; i += 512){
        uint2 pr = staged[i];
        int p = atomicAdd(&cur[pr.y & (BIN_NODES - 1)], 1);
        eidx[p] = (int)pr.x;
    }
}

// ---------------- weight prep: split W into bf16 hi/lo, k-packed B' layout ----

__global__ void k_prepw(const float* __restrict__ W1, const float* __restrict__ W2,
                        const float* __restrict__ W3, unsigned short* __restrict__ Bp){
    int t = blockIdx.x * 256 + threadIdx.x;          // 0..49151
    if (t >= 49152) return;
    int w = t >> 14;
    int r = t & 16383;
    int k = r >> 7, j = r & 127;
    const float* W = (w == 0) ? W1 : (w == 1) ? W2 : W3;
    float val = W[j * 128 + k];
    unsigned short hi = bf16s(val);
    unsigned short lo = bf16s(val - bf2f(hi));
    int idx = (k >> 3) * 1024 + j * 8 + (k & 7);
    Bp[w * 32768 + idx] = hi;
    Bp[w * 32768 + 16384 + idx] = lo;
}

// ---------------- input split: fp32 -> bf16 hi/lo ----------------

__global__ void k_split(const float* __restrict__ X, unsigned short* __restrict__ Xhi,
                        unsigned short* __restrict__ Xlo, int nquads){
    int t = blockIdx.x * 256 + threadIdx.x;
    if (t >= nquads) return;
    float4 v = ((const float4*)X)[t];
    ushort4 hi, lo;
    hi.x = bf16s(v.x); lo.x = bf16s(v.x - bf2f(hi.x));
    hi.y = bf16s(v.y); lo.y = bf16s(v.y - bf2f(hi.y));
    hi.z = bf16s(v.z); lo.z = bf16s(v.z - bf2f(hi.z));
    hi.w = bf16s(v.w); lo.w = bf16s(v.w - bf2f(hi.w));
    ((ushort4*)Xhi)[t] = hi;
    ((ushort4*)Xlo)[t] = lo;
}

// ---------------- split-bf16 MFMA GEMM + fused attention coefficients --------

__global__ __launch_bounds__(256) void k_mgemm(
        const unsigned short* __restrict__ Xhi, const unsigned short* __restrict__ Xlo,
        const unsigned short* __restrict__ Bp,
        const float* __restrict__ aw_s, const float* __restrict__ aw_d,
        unsigned short* __restrict__ Hh,
        float* __restrict__ asrc, float* __restrict__ adst, int n_rows){
    __shared__ unsigned short Bs[8192];          // 16 KB: hi + lo, one K-slice
    int lane = threadIdx.x & 63;
    int wv   = threadIdx.x >> 6;
    int li = lane & 15, quad = lane >> 4;
    int r0 = blockIdx.x * 128 + wv * 32;

    int row0 = r0 + li;
    int row1 = r0 + 16 + li;
    int rc0 = row0 < n_rows ? row0 : 0;
    int rc1 = row1 < n_rows ? row1 : 0;

    v8s ah0[4], al0[4], ah1[4], al1[4];
    #pragma unroll
    for (int ks = 0; ks < 4; ks++){
        int koff = ks * 32 + quad * 8;
        ah0[ks] = *(const v8s*)(Xhi + (size_t)rc0 * 128 + koff);
        al0[ks] = *(const v8s*)(Xlo + (size_t)rc0 * 128 + koff);
        ah1[ks] = *(const v8s*)(Xhi + (size_t)rc1 * 128 + koff);
        al1[ks] = *(const v8s*)(Xlo + (size_t)rc1 * 128 + koff);
    }

    v4f acc[2][8];
    #pragma unroll
    for (int m = 0; m < 2; m++)
        #pragma unroll
        for (int t = 0; t < 8; t++)
            acc[m][t] = (v4f){0.f, 0.f, 0.f, 0.f};

    #pragma unroll
    for (int ks = 0; ks < 4; ks++){
        if (ks) __syncthreads();
        #pragma unroll
        for (int i = 0; i < 2; i++){
            int idx = threadIdx.x + i * 256;
            ((float4*)Bs)[idx]          = ((const float4*)(Bp + ks * 4096))[idx];
            ((float4*)(Bs + 4096))[idx] = ((const float4*)(Bp + 16384 + ks * 4096))[idx];
        }
        __syncthreads();
        #pragma unroll
        for (int t = 0; t < 8; t++){
            int bo = quad * 1024 + (t * 16 + li) * 8;
            v8s bh = *(const v8s*)(Bs + bo);
            v8s bl = *(const v8s*)(Bs + 4096 + bo);
            acc[0][t] = __builtin_amdgcn_mfma_f32_16x16x32_bf16(ah0[ks], bh, acc[0][t], 0, 0, 0);
            acc[0][t] = __builtin_amdgcn_mfma_f32_16x16x32_bf16(ah0[ks], bl, acc[0][t], 0, 0, 0);
            acc[0][t] = __builtin_amdgcn_mfma_f32_16x16x32_bf16(al0[ks], bh, acc[0][t], 0, 0, 0);
            acc[1][t] = __builtin_amdgcn_mfma_f32_16x16x32_bf16(ah1[ks], bh, acc[1][t], 0, 0, 0);
            acc[1][t] = __builtin_amdgcn_mfma_f32_16x16x32_bf16(ah1[ks], bl, acc[1][t], 0, 0, 0);
            acc[1][t] = __builtin_amdgcn_mfma_f32_16x16x32_bf16(al1[ks], bh, acc[1][t], 0, 0, 0);
        }
    }

    // epilogue 1: fp16 mirror
    #pragma unroll
    for (int m = 0; m < 2; m++){
        #pragma unroll
        for (int t = 0; t < 8; t++){
            #pragma unroll
            for (int r = 0; r < 4; r++){
                float v  = acc[m][t][r];
                float vo = __shfl_xor(v, 1);
                if (!(li & 1)){
                    int row = r0 + m * 16 + quad * 4 + r;
                    if (row < n_rows)
                        *(unsigned*)(Hh + (size_t)row * 128 + t * 16 + li) = f2h2(v, vo);
                }
            }
        }
    }

    // epilogue 2: fused attention coefficients
    float as8[8], ad8[8];
    #pragma unroll
    for (int t = 0; t < 8; t++){
        as8[t] = aw_s[t * 16 + li];
        ad8[t] = aw_d[t * 16 + li];
    }
    #pragma unroll
    for (int m = 0; m < 2; m++){
        #pragma unroll
        for (int r = 0; r < 4; r++){
            float sp[4], dp[4];
            #pragma unroll
            for (int h = 0; h < 4; h++){
                sp[h] = acc[m][2*h][r] * as8[2*h] + acc[m][2*h+1][r] * as8[2*h+1];
                dp[h] = acc[m][2*h][r] * ad8[2*h] + acc[m][2*h+1][r] * ad8[2*h+1];
            }
            #pragma unroll
            for (int off = 1; off < 16; off <<= 1){
                #pragma unroll
                for (int h = 0; h < 4; h++){
                    sp[h] += __shfl_xor(sp[h], off);
                    dp[h] += __shfl_xor(dp[h], off);
                }
            }
            if (li == 0){
                int row = r0 + m * 16 + quad * 4 + r;
                if (row < n_rows){
                    ((float4*)asrc)[row] = make_float4(sp[0], sp[1], sp[2], sp[3]);
                    ((float4*)adst)[row] = make_float4(dp[0], dp[1], dp[2], dp[3]);
                }
            }
        }
    }
}

// ---------------- softmax + aggregation, one wave per node ----------------

#define AGGR_CAP 96

template<int MEAN>
__global__ __launch_bounds__(256) void k_aggr(
        const unsigned* __restrict__ Hh,
        const float* __restrict__ asrc, const float* __restrict__ adst,
        const int* __restrict__ rowptr, const int* __restrict__ eidx,
        const float* __restrict__ bias,
        unsigned short* __restrict__ Oh, unsigned short* __restrict__ Ol,
        float* __restrict__ Of, int n_nodes){
    __shared__ float wls[4][AGGR_CAP * 4];     // 6 KB
    int lane = threadIdx.x & 63;
    int wid  = threadIdx.x >> 6;
    int n = blockIdx.x * 4 + wid;
    if (n >= n_nodes) return;
    int row0 = rowptr[n];
    int deg  = rowptr[n + 1] - row0;
    float4 ad = ((const float4*)adst)[n];
    float* wl = wls[wid];
    const int* ep = eidx + row0;

    float e0 = -1e30f, e1 = -1e30f, e2 = -1e30f, e3 = -1e30f;
    if (lane < deg){
        int s = ep[lane];
        float4 av = ((const float4*)asrc)[s];
        e0 = lrelu(av.x + ad.x); e1 = lrelu(av.y + ad.y);
        e2 = lrelu(av.z + ad.z); e3 = lrelu(av.w + ad.w);
    }
    float m0 = e0, m1 = e1, m2 = e2, m3 = e3;
    for (int i = lane + 64; i < deg; i += 64){
        int s = eidx[row0 + i];
        float4 av = ((const float4*)asrc)[s];
        m0 = fmaxf(m0, lrelu(av.x + ad.x));
        m1 = fmaxf(m1, lrelu(av.y + ad.y));
        m2 = fmaxf(m2, lrelu(av.z + ad.z));
        m3 = fmaxf(m3, lrelu(av.w + ad.w));
    }
    #pragma unroll
    for (int off = 32; off; off >>= 1){
        m0 = fmaxf(m0, __shfl_xor(m0, off));
        m1 = fmaxf(m1, __shfl_xor(m1, off));
        m2 = fmaxf(m2, __shfl_xor(m2, off));
        m3 = fmaxf(m3, __shfl_xor(m3, off));
    }

    float d0 = 0.f, d1 = 0.f, d2 = 0.f, d3 = 0.f;
    if (lane < deg){
        float x0 = __expf(e0 - m0), x1 = __expf(e1 - m1);
        float x2 = __expf(e2 - m2), x3 = __expf(e3 - m3);
        d0 = x0; d1 = x1; d2 = x2; d3 = x3;
        ((float4*)wl)[lane] = make_float4(x0, x1, x2, x3);
    }
    for (int i = lane + 64; i < deg; i += 64){
        int s = eidx[row0 + i];
        float4 av = ((const float4*)asrc)[s];
        float x0 = __expf(lrelu(av.x + ad.x) - m0);
        float x1 = __expf(lrelu(av.y + ad.y) - m1);
        float x2 = __expf(lrelu(av.z + ad.z) - m2);
        float x3 = __expf(lrelu(av.w + ad.w) - m3);
        d0 += x0; d1 += x1; d2 += x2; d3 += x3;
        if (i < AGGR_CAP) ((float4*)wl)[i] = make_float4(x0, x1, x2, x3);
    }
    #pragma unroll
    for (int off = 32; off; off >>= 1){
        d0 += __shfl_xor(d0, off);
        d1 += __shfl_xor(d1, off);
        d2 += __shfl_xor(d2, off);
        d3 += __shfl_xor(d3, off);
    }
    int hd = lane >> 4;
    float mh  = hd == 0 ? m0 : hd == 1 ? m1 : hd == 2 ? m2 : m3;
    float rdh = 1.f / (hd == 0 ? d0 : hd == 1 ? d1 : hd == 2 ? d2 : d3);
    float adh = hd == 0 ? ad.x : hd == 1 ? ad.y : hd == 2 ? ad.z : ad.w;

    float accx = 0.f, accy = 0.f;
    int c = lane * 2;
    const float* wlh = wl + hd;
    int cap = deg < AGGR_CAP ? deg : AGGR_CAP;
    int i = 0;
    for (; i + 8 <= cap; i += 8){
        int s[8];
        #pragma unroll
        for (int j = 0; j < 8; j++) s[j] = ep[i + j];
        unsigned hw[8];
        #pragma unroll
        for (int j = 0; j < 8; j++) hw[j] = Hh[(size_t)s[j] * 64 + lane];
        #pragma unroll
        for (int j = 0; j < 8; j++){
            float w = wlh[(i + j) * 4];
            float2 hv = h2f2(hw[j]);
            accx += w * hv.x;
            accy += w * hv.y;
        }
    }
    for (; i < cap; i++){
        int s = ep[i];
        float w = wlh[i * 4];
        float2 hv = h2f2(Hh[(size_t)s * 64 + lane]);
        accx += w * hv.x;
        accy += w * hv.y;
    }
    for (; i < deg; i++){
        int s = ep[i];
        float w = __expf(lrelu(asrc[s * 4 + hd] + adh) - mh);
        float2 hv = h2f2(Hh[(size_t)s * 64 + lane]);
        accx += w * hv.x;
        accy += w * hv.y;
    }
    accx *= rdh; accy *= rdh;

    if (!MEAN){
        float ox = elu_f(accx + bias[c]);
        float oy = elu_f(accy + bias[c + 1]);
        unsigned short hx = bf16s(ox), hy = bf16s(oy);
        unsigned short lx = bf16s(ox - bf2f(hx)), ly = bf16s(oy - bf2f(hy));
        *(ushort2*)(Oh + (size_t)n * 128 + c) = make_ushort2(hx, hy);
        *(ushort2*)(Ol + (size_t)n * 128 + c) = make_ushort2(lx, ly);
    } else {
        float sx = accx, sy = accy;
        sx += __shfl_xor(sx, 16); sy += __shfl_xor(sy, 16);
        sx += __shfl_xor(sx, 32); sy += __shfl_xor(sy, 32);
        if (lane < 16){
            int cc = lane * 2;
            float ox = elu_f(sx * 0.25f + bias[cc]);
            float oy = elu_f(sy * 0.25f + bias[cc + 1]);
            *(float2*)(Of + (size_t)n * 32 + cc) = make_float2(ox, oy);
        }
    }
}

// ---------------- readout ----------------

__global__ void k_readout(const float* __restrict__ H3, const int* __restrict__ batch,
                          const float* __restrict__ lw, const float* __restrict__ lb,
                          float* __restrict__ pool, float* __restrict__ cnt, int n_nodes){
    __shared__ float pl[64];
    __shared__ float cl[64];
    if (threadIdx.x < 64){ pl[threadIdx.x] = 0.f; cl[threadIdx.x] = 0.f; }
    __syncthreads();
    int n = blockIdx.x * 256 + threadIdx.x;
    if (n < n_nodes){
        const float4* hp = (const float4*)(H3 + (size_t)n * 32);
        const float4* wp = (const float4*)lw;
        float y = 0.f;
        #pragma unroll
        for (int i = 0; i < 8; i++){
            float4 h4 = hp[i], w4 = wp[i];
            y += h4.x * w4.x + h4.y * w4.y + h4.z * w4.z + h4.w * w4.w;
        }
        y += lb[0];
        int b = batch[n];
        atomicAdd(&pl[b], y);
        atomicAdd(&cl[b], 1.f);
    }
    __syncthreads();
    if (threadIdx.x < 64 && cl[threadIdx.x] != 0.f){
        atomicAdd(&pool[threadIdx.x], pl[threadIdx.x]);
        atomicAdd(&cnt[threadIdx.x], cl[threadIdx.x]);
    }
}

__global__ void k_final(const float* __restrict__ pool, const float* __restrict__ cnt,
                        float* __restrict__ out){
    int g = threadIdx.x;
    if (g < 64) out[g] = (cnt[g] > 0.f) ? pool[g] / cnt[g] : 0.f;
}

// ---------------- launch ----------------

extern "C" void kernel_launch(void* const* d_in, const int* in_sizes, int n_in,
                              void* d_out, int out_size, void* d_ws, size_t ws_size,
                              hipStream_t stream){
    const float* x   = (const float*)d_in[0];
    const int*   ei  = (const int*)  d_in[1];
    const int*   bat = (const int*)  d_in[2];
    const float* W1  = (const float*)d_in[3];
    const float* a1s = (const float*)d_in[4];
    const float* a1d = (const float*)d_in[5];
    const float* b1  = (const float*)d_in[6];
    const float* W2  = (const float*)d_in[7];
    const float* a2s = (const float*)d_in[8];
    const float* a2d = (const float*)d_in[9];
    const float* b2  = (const float*)d_in[10];
    const float* W3  = (const float*)d_in[11];
    const float* a3s = (const float*)d_in[12];
    const float* a3d = (const float*)d_in[13];
    const float* b3  = (const float*)d_in[14];
    const float* lw  = (const float*)d_in[15];
    const float* lb  = (const float*)d_in[16];
    (void)n_in; (void)out_size; (void)ws_size;

    const int n_nodes = in_sizes[0] / D1;      // 100000
    const int n_edges = in_sizes[1] / 2;       // 1600000
    const int etot    = n_edges + n_nodes;     // 1700000
    const int nbin    = (n_nodes + BIN_NODES - 1) >> NODE_SHIFT;   // 196

    char* p = (char*)d_ws;
    size_t off = 0;
    auto alloc = [&](size_t bytes) -> char* {
        char* r = p + off;
        off = (off + bytes + 511) & ~(size_t)511;
        return r;
    };
    unsigned short* Hh   = (unsigned short*)alloc((size_t)n_nodes * 128 * 2); // 25.6 MB
    unsigned short* Xhi  = (unsigned short*)alloc((size_t)n_nodes * 128 * 2); // 25.6 MB
    unsigned short* Xlo  = (unsigned short*)alloc((size_t)n_nodes * 128 * 2); // 25.6 MB
    float*          asrc = (float*)alloc((size_t)n_nodes * 4 * 4);
    float*          adst = (float*)alloc((size_t)n_nodes * 4 * 4);
    unsigned short* Bp   = (unsigned short*)alloc(3 * 32768 * 2);
    int*   rowptr  = (int*)alloc((size_t)(n_nodes + 1) * 4);
    int*   eidx    = (int*)alloc((size_t)etot * 4);
    uint2* staged  = (uint2*)alloc((size_t)etot * 8);              // 13.6 MB
    int*   binCnt  = (int*)alloc(MAXBIN * 4);
    int*   binStart= (int*)alloc((MAXBIN + 1) * 4);
    int*   binCur  = (int*)alloc(MAXBIN * 4);
    float* pool    = (float*)alloc(64 * 4);
    float* cnt     = (float*)alloc(64 * 4);
    float* h3      = (float*)Xhi;              // alias: Xhi not read by layer-3 aggr

    hipMemsetAsync(binCnt, 0, MAXBIN * 4, stream);
    hipMemsetAsync(pool, 0, 64 * 4, stream);
    hipMemsetAsync(cnt, 0, 64 * 4, stream);

    k_prepw<<<192, 256, 0, stream>>>(W1, W2, W3, Bp);

    int cb = (etot + 4095) / 4096;             // 416 chunks
    kb_hist<<<cb, 256, 0, stream>>>(ei, binCnt, n_edges, etot, nbin);
    kb_scan<<<1, 64, 0, stream>>>(binCnt, binStart, binCur, nbin, rowptr, n_nodes, etot);
    kb_scatter<<<cb, 256, 0, stream>>>(ei, binCur, staged, n_edges, etot, nbin);
    kb_final<<<nbin, 512, 0, stream>>>(staged, binStart, rowptr, eidx, n_nodes);

    int nquads = n_nodes * 32;                 // n*128/4
    k_split<<<(nquads + 255) / 256, 256, 0, stream>>>(x, Xhi, Xlo, nquads);

    int mb = (n_nodes + 127) / 128;
    int rb = (n_nodes + 3) / 4;

    // layer 1
    k_mgemm<<<mb, 256, 0, stream>>>(Xhi, Xlo, Bp, a1s, a1d, Hh, asrc, adst, n_nodes);
    k_aggr<0><<<rb, 256, 0, stream>>>((const unsigned*)Hh, asrc, adst, rowptr, eidx,
                                      b1, Xhi, Xlo, nullptr, n_nodes);
    // layer 2
    k_mgemm<<<mb, 256, 0, stream>>>(Xhi, Xlo, Bp + 32768, a2s, a2d, Hh, asrc, adst, n_nodes);
    k_aggr<0><<<rb, 256, 0, stream>>>((const unsigned*)Hh, asrc, adst, rowptr, eidx,
                                      b2, Xhi, Xlo, nullptr, n_nodes);
    // layer 3
    k_mgemm<<<mb, 256, 0, stream>>>(Xhi, Xlo, Bp + 65536, a3s, a3d, Hh, asrc, adst, n_nodes);
    k_aggr<1><<<rb, 256, 0, stream>>>((const unsigned*)Hh, asrc, adst, rowptr, eidx,
                                      b3, nullptr, nullptr, h3, n_nodes);

    int ob = (n_nodes + 255) / 256;
    k_readout<<<ob, 256, 0, stream>>>(h3, bat, lw, lb, pool, cnt, n_nodes);
    k_final<<<1, 64, 0, stream>>>(pool, cnt, (float*)d_out);
}